// Round 7
// baseline (280.059 us; speedup 1.0000x reference)
//
#include <hip/hip_runtime.h>
#include <hip/hip_fp16.h>

// Problem geometry: inputs (B=2, D=64, H=64, W=64, C=32) fp32, C innermost.
// Pass1: Sobel (VALID) -> mag = sqrt(gx^2+gy^2+gz^2) at 62^3 per (b,c)
// Pass2: Sobel on mag -> out = sqrt(gx^2+gy^2) + gz^2 at 60^3
// Result: mean(|out_pred - out_hr|) over 2*32*60^3 = 13,824,000 elems.
//
// R11: P2 wave-count x4. Accounting over R4-R10: P1 serves ~256MB (incl.
// 2x y-halo via L3) in 44us = 5.8 TB/s = effective ceiling -> P1 is DONE.
// P2 serves 70MB in 44.8us = 1.6 TB/s, occupancy 18%, VGPR 60 -> latency
// bound, too few waves (720 blocks = 11 waves/CU). R6/R10 proved widening
// per-thread state backfires (VGPR x MLP trap). Fix: split the y-pair across
// threads (1 output row/thread, 3-row window, state 36 floats) and x into
// 8-wide tiles: block = 8x*16cp*2y, grid (240,6) = 1440 blocks/batch, same
// traffic (y-overlap hits L1, same CU; channel pairs keep 64B line density).
// P1 + chain + fused finalize verbatim R7.

constexpr int BDIM = 256;
constexpr size_t IN_B = 8388608;   // floats per batch
constexpr int IN_D = 131072;       // floats per z-plane
constexpr int IN_H = 2048;         // floats per y-row
constexpr int M = 62;              // mag spatial dim
constexpr int F = 60;              // final spatial dim
constexpr int C = 32;
constexpr int MROW = M * C;                      // 1984 halves per mag row
constexpr size_t MAGSZ = (size_t)M * M * MROW;   // halves per mag buffer
constexpr size_t PLANE = (size_t)M * MROW;       // halves per mag z-plane
constexpr unsigned NPART = 2880;                 // 1440 blocks x 2 batches

__device__ __forceinline__ float4 ld4(const float* p) {
    return *reinterpret_cast<const float4*>(p);
}
__device__ __forceinline__ float2 ldh2(const __half* p) {
    return __half22float2(*reinterpret_cast<const __half2*>(p));
}
__device__ __forceinline__ float4 sm3(float4 a, float4 b, float4 c) {
    return make_float4(a.x + 2.f * b.x + c.x, a.y + 2.f * b.y + c.y,
                       a.z + 2.f * b.z + c.z, a.w + 2.f * b.w + c.w);
}
__device__ __forceinline__ float4 df2(float4 a, float4 c) {
    return make_float4(c.x - a.x, c.y - a.y, c.z - a.z, c.w - a.w);
}

// ===================== Pass 1 (R7 body, verbatim, proven) =====================
struct P1W { float4 A[2], B[2], C[2]; };

__device__ __forceinline__ void p1_plane(const float* __restrict__ col, size_t zoff,
                                         P1W& W)
{
    float4 S[4], D[4];
#pragma unroll
    for (int r = 0; r < 4; ++r) {
        const float* p = col + zoff + (size_t)r * IN_H;
        float4 a = ld4(p), b = ld4(p + C), c = ld4(p + 2 * C);
        S[r] = sm3(a, b, c);
        D[r] = df2(a, c);
    }
#pragma unroll
    for (int k = 0; k < 2; ++k) {
        W.A[k] = sm3(S[k], S[k+1], S[k+2]);
        W.B[k] = df2(S[k], S[k+2]);
        W.C[k] = sm3(D[k], D[k+1], D[k+2]);
    }
}

__device__ __forceinline__ void p1_emit(const P1W& W0, const P1W& W1, const P1W& W2,
                                        __half* __restrict__ mag, size_t cb,
                                        int z, int y0, bool wr)
{
    if (!wr) return;
#pragma unroll
    for (int k = 0; k < 2; ++k) {
        float4 gx = df2(W0.A[k], W2.A[k]);
        float4 gy = sm3(W0.B[k], W1.B[k], W2.B[k]);
        float4 gz = sm3(W0.C[k], W1.C[k], W2.C[k]);
        float m0 = sqrtf(gx.x * gx.x + gy.x * gy.x + gz.x * gz.x);
        float m1 = sqrtf(gx.y * gx.y + gy.y * gy.y + gz.y * gz.y);
        float m2 = sqrtf(gx.z * gx.z + gy.z * gy.z + gz.z * gz.z);
        float m3 = sqrtf(gx.w * gx.w + gy.w * gy.w + gz.w * gz.w);
        union { __half2 h[2]; float2 f; } u;
        u.h[0] = __floats2half2_rn(m0, m1);
        u.h[1] = __floats2half2_rn(m2, m3);
        *reinterpret_cast<float2*>(mag + ((size_t)z * M + (y0 + k)) * MROW + cb)
            = u.f;
    }
}

__device__ __forceinline__ void p1_unit(const float* __restrict__ in,
                                        __half* __restrict__ mag,
                                        int b, int bx, int zc, int tid)
{
    const int xt = bx & 1, yt = bx >> 1;
    const int c4 = (tid & 7) << 2;           // channel base 0..28
    const int xl = tid >> 3;                 // 0..31
    const int x  = xt * 30 + xl;             // output x in [0,62)
    const bool wr = (xt == 0) || (xl >= 2);  // tile1 skips duplicated x=30,31
    const int y0 = yt * 2;
    const int z0 = zc * 8;
    const int zn = min(8, M - z0);           // 8, last chunk 6

    const float* col = in + (size_t)b * IN_B + (size_t)y0 * IN_H
                          + (size_t)x * C + c4;
    const size_t cb = (size_t)x * C + c4;

    P1W W0, W1, W2;
    p1_plane(col, (size_t)(z0 + 0) * IN_D, W0);
    p1_plane(col, (size_t)(z0 + 1) * IN_D, W1);
    int z = 0;
    while (true) {
        p1_plane(col, (size_t)(z0 + z + 2) * IN_D, W2);
        p1_emit(W0, W1, W2, mag, cb, z0 + z, y0, wr);
        if (++z >= zn) break;
        p1_plane(col, (size_t)(z0 + z + 2) * IN_D, W0);
        p1_emit(W1, W2, W0, mag, cb, z0 + z, y0, wr);
        if (++z >= zn) break;
        p1_plane(col, (size_t)(z0 + z + 2) * IN_D, W1);
        p1_emit(W2, W0, W1, mag, cb, z0 + z, y0, wr);
        if (++z >= zn) break;
    }
}

__global__ __launch_bounds__(BDIM) void sobel_mag_v11(
    const float* __restrict__ pred, const float* __restrict__ hr,
    __half* __restrict__ magP, __half* __restrict__ magH,
    int b, unsigned* __restrict__ counter, int zeroCtr)
{
    if (zeroCtr && blockIdx.x == 0 && blockIdx.y == 0 && blockIdx.z == 0 &&
        threadIdx.x == 0)
        __hip_atomic_store(counter, 0u, __ATOMIC_RELAXED,
                           __HIP_MEMORY_SCOPE_AGENT);
    const float* in = blockIdx.z ? hr : pred;
    __half* mag = blockIdx.z ? magH : magP;
    p1_unit(in, mag, b, blockIdx.x, blockIdx.y, threadIdx.x);
}

// ===== Pass 2 v11: 1 output row/thread, 3-row window, 2x blocks, low VGPR =====
struct P2S { float2 A, B, C; };   // per-plane partials for ONE output row

__device__ __forceinline__ void p2_plane_v11(const __half* __restrict__ col,
                                             size_t zoff, P2S& W)
{
    float2 SX[3], DX[3];
#pragma unroll
    for (int j = 0; j < 3; ++j) {
        const __half* p = col + zoff + (size_t)j * MROW;
        float2 a = ldh2(p), b = ldh2(p + C), c = ldh2(p + 2 * C);
        SX[j] = make_float2(a.x + 2.f * b.x + c.x, a.y + 2.f * b.y + c.y);
        DX[j] = make_float2(c.x - a.x, c.y - a.y);
    }
    W.A = make_float2(SX[0].x + 2.f * SX[1].x + SX[2].x,
                      SX[0].y + 2.f * SX[1].y + SX[2].y);
    W.B = make_float2(SX[2].x - SX[0].x, SX[2].y - SX[0].y);
    W.C = make_float2(DX[0].x + 2.f * DX[1].x + DX[2].x,
                      DX[0].y + 2.f * DX[1].y + DX[2].y);
}

__device__ __forceinline__ void p2_emit_v11(const P2S& P0, const P2S& P1, const P2S& P2,
                                            const P2S& H0, const P2S& H1, const P2S& H2,
                                            float& acc)
{
    float gxPx = P2.A.x - P0.A.x;
    float gxPy = P2.A.y - P0.A.y;
    float gyPx = P0.B.x + 2.f * P1.B.x + P2.B.x;
    float gyPy = P0.B.y + 2.f * P1.B.y + P2.B.y;
    float gzPx = P0.C.x + 2.f * P1.C.x + P2.C.x;
    float gzPy = P0.C.y + 2.f * P1.C.y + P2.C.y;
    float gxHx = H2.A.x - H0.A.x;
    float gxHy = H2.A.y - H0.A.y;
    float gyHx = H0.B.x + 2.f * H1.B.x + H2.B.x;
    float gyHy = H0.B.y + 2.f * H1.B.y + H2.B.y;
    float gzHx = H0.C.x + 2.f * H1.C.x + H2.C.x;
    float gzHy = H0.C.y + 2.f * H1.C.y + H2.C.y;
    float oPx = sqrtf(gxPx * gxPx + gyPx * gyPx) + gzPx * gzPx;
    float oPy = sqrtf(gxPy * gxPy + gyPy * gyPy) + gzPy * gzPy;
    float oHx = sqrtf(gxHx * gxHx + gyHx * gyHx) + gzHx * gzHx;
    float oHy = sqrtf(gxHy * gxHy + gyHy * gyHy) + gzHy * gzHy;
    acc += fabsf(oPx - oHx) + fabsf(oPy - oHy);
}

// grid (240, 6): bx -> xt = bx&7 (8 x-tiles of 8), yt = bx>>3 (30 y-tiles of 2).
// 256 threads = yb(1 bit) x xl(3 bits) x cp(4 bits). z-chunk 10 (planes z0..z0+11).
__global__ __launch_bounds__(BDIM) void sobel2_v11(
    const __half* __restrict__ magP, const __half* __restrict__ magH,
    int b, float* __restrict__ partial, unsigned* __restrict__ counter,
    float* __restrict__ out)
{
    const int bx = blockIdx.x;
    const int xt = bx & 7, yt = bx >> 3;    // xt 0..7, yt 0..29
    const int zc = blockIdx.y;              // 0..5
    const int z0 = zc * 10;
    const int tid = threadIdx.x;
    const int yb = tid >> 7;                // 0/1
    const int xl = (tid >> 4) & 7;          // 0..7
    const int cp = tid & 15;                // 0..15
    const int y  = yt * 2 + yb;             // output row, 0..59; reads rows y..y+2
    const int c2 = cp << 1;
    const int xo = xt * 8 + xl;             // output x, 0..63
    const bool wr = xo < F;                 // last tile: xl<4 valid
    const int xld = min(xo, F - 1);         // clamped load base (cols xld..xld+2 <= 61)

    const size_t colo = (size_t)y * MROW + (size_t)xld * C + c2;
    const __half* colP = magP + colo;
    const __half* colH = magH + colo;

    P2S P0, P1, P2, H0, H1, H2;
    float acc = 0.f;
    p2_plane_v11(colP, (size_t)(z0 + 0) * PLANE, P0);
    p2_plane_v11(colH, (size_t)(z0 + 0) * PLANE, H0);
    p2_plane_v11(colP, (size_t)(z0 + 1) * PLANE, P1);
    p2_plane_v11(colH, (size_t)(z0 + 1) * PLANE, H1);
    int z = 0;
    while (true) {
        p2_plane_v11(colP, (size_t)(z0 + z + 2) * PLANE, P2);
        p2_plane_v11(colH, (size_t)(z0 + z + 2) * PLANE, H2);
        if (wr) p2_emit_v11(P0, P1, P2, H0, H1, H2, acc);
        if (++z >= 10) break;
        p2_plane_v11(colP, (size_t)(z0 + z + 2) * PLANE, P0);
        p2_plane_v11(colH, (size_t)(z0 + z + 2) * PLANE, H0);
        if (wr) p2_emit_v11(P1, P2, P0, H1, H2, H0, acc);
        if (++z >= 10) break;
        p2_plane_v11(colP, (size_t)(z0 + z + 2) * PLANE, P1);
        p2_plane_v11(colH, (size_t)(z0 + z + 2) * PLANE, H1);
        if (wr) p2_emit_v11(P2, P0, P1, H2, H0, H1, acc);
        if (++z >= 10) break;
    }

    // block reduction + globally-last-block finalize
    for (int o = 32; o > 0; o >>= 1) acc += __shfl_down(acc, o, 64);
    __shared__ float sred[BDIM / 64];
    __shared__ int isLast;
    __shared__ double sd[BDIM / 64];
    const int lane = tid & 63, wv = tid >> 6;
    if (lane == 0) sred[wv] = acc;
    __syncthreads();
    if (tid == 0) {
        float t = 0.f;
#pragma unroll
        for (int i = 0; i < BDIM / 64; ++i) t += sred[i];
        const size_t pidx = (size_t)b * 1440 + (size_t)zc * 240 + bx;
        __hip_atomic_store(&partial[pidx], t, __ATOMIC_RELAXED,
                           __HIP_MEMORY_SCOPE_AGENT);
        const unsigned old = __hip_atomic_fetch_add(counter, 1u, __ATOMIC_ACQ_REL,
                                                    __HIP_MEMORY_SCOPE_AGENT);
        isLast = (old == NPART - 1u) ? 1 : 0;
    }
    __syncthreads();
    if (isLast) {
        double a = 0.0;
        for (unsigned i = tid; i < NPART; i += BDIM)
            a += (double)__hip_atomic_load(&partial[i], __ATOMIC_RELAXED,
                                           __HIP_MEMORY_SCOPE_AGENT);
        for (int o = 32; o > 0; o >>= 1) a += __shfl_down(a, o, 64);
        if (lane == 0) sd[wv] = a;
        __syncthreads();
        if (tid == 0) {
            double t = 0.0;
#pragma unroll
            for (int i = 0; i < BDIM / 64; ++i) t += sd[i];
            out[0] = (float)(t / 13824000.0);
        }
    }
}

extern "C" void kernel_launch(void* const* d_in, const int* in_sizes, int n_in,
                              void* d_out, int out_size, void* d_ws, size_t ws_size,
                              hipStream_t stream)
{
    const float* pred = (const float*)d_in[0];
    const float* hr   = (const float*)d_in[1];

    // ws layout: [0, 11.5KB): 2880 float partials
    //            [32KB): unsigned last-block counter (zeroed by P1(b0))
    //            [64KB, ...): 2 fp16 mag buffers (~29.2 MB), reused per batch
    float* partial    = (float*)d_ws;
    unsigned* counter = (unsigned*)((char*)d_ws + 32768);
    __half* magP = (__half*)((char*)d_ws + 65536);
    __half* magH = magP + MAGSZ;

    for (int b = 0; b < 2; ++b) {
        sobel_mag_v11<<<dim3(62, 8, 2), BDIM, 0, stream>>>(
            pred, hr, magP, magH, b, counter, b == 0 ? 1 : 0);
        sobel2_v11<<<dim3(240, 6), BDIM, 0, stream>>>(
            magP, magH, b, partial, counter, (float*)d_out);
    }
}